// Round 9
// baseline (13187.358 us; speedup 1.0000x reference)
//
#include <hip/hip_runtime.h>
#include <math.h>

#define NPIX  25600      // 160*160
#define NANCH 76800      // 3*NPIX

// output layout (float elements)
constexpr int OUT_ANCH = 0;        // 76800*4
constexpr int OUT_OBJ  = 307200;   // 76800
constexpr int OUT_DELT = 384000;   // 76800*4
constexpr int OUT_FL   = 691200;   // 1000
constexpr int OUT_FB   = 692200;   // 1000*4

// workspace layout (bytes)
constexpr size_t Y_OFF     = 0;                        // 256*25600*4 = 26,214,400 (f32)
constexpr size_t PROPS_OFF = 26214400;                 // 76800*4*8
constexpr size_t LGM_OFF   = PROPS_OFF + 2457600;      // 76800*8
constexpr size_t TSC_OFF   = LGM_OFF + 614400 + 49152; // 2000*8 -> 16384
constexpr size_t TBOX_OFF  = TSC_OFF + 16384;          // 2000*4*8 -> 65536

// ---------------------------------------------------------------- init
__global__ __launch_bounds__(256) void init_misc(float* __restrict__ out) {
  int t = blockIdx.x * 256 + threadIdx.x;
  if (t < 1000) out[OUT_FL + t] = -1e9f;
  if (t < 4000) out[OUT_FB + t] = 0.f;
}

// ---------------------------------------------------------------- naive direct conv + bn + relu
// PROBE: f32 accumulation, REVERSED order (ic 255->0, taps 8->0) for maximum
// decorrelation from R1's f32 order and from exact f64 (R5).
__global__ __launch_bounds__(256) void conv_naive_f32r(
    const float* __restrict__ x, const float* __restrict__ w,
    const float* __restrict__ bv, const float* __restrict__ gamma,
    const float* __restrict__ beta, const float* __restrict__ mean,
    const float* __restrict__ var, float* __restrict__ y) {
  const int oc = blockIdx.y;
  const int p  = blockIdx.x * 256 + threadIdx.x;
  const int h  = p / 160, wv = p - h * 160;
  const float* wb = w + (size_t)oc * 2304;
  const bool h0 = (h > 0), h2 = (h < 159), w0 = (wv > 0), w2 = (wv < 159);
  float acc = 0.f;
  for (int ic = 255; ic >= 0; --ic) {
    const float* xb = x + (size_t)ic * NPIX + p;
    const float* wo = wb + ic * 9;           // wave-uniform -> scalar loads
    // taps in reversed order 8..0
    if (h2) {
      if (w2) acc = fmaf(xb[161], wo[8], acc);
      acc = fmaf(xb[160], wo[7], acc);
      if (w0) acc = fmaf(xb[159], wo[6], acc);
    }
    if (w2) acc = fmaf(xb[1], wo[5], acc);
    acc = fmaf(xb[0], wo[4], acc);
    if (w0) acc = fmaf(xb[-1], wo[3], acc);
    if (h0) {
      if (w2) acc = fmaf(xb[-159], wo[2], acc);
      acc = fmaf(xb[-160], wo[1], acc);
      if (w0) acc = fmaf(xb[-161], wo[0], acc);
    }
  }
  float sc = gamma[oc] / sqrtf(var[oc] + 1e-5f);
  float sh = (bv[oc] - mean[oc]) * sc + beta[oc];
  float v = fmaf(acc, sc, sh);
  y[(size_t)oc * NPIX + p] = (v > 0.f) ? v : 0.f;
}

// ---------------------------------------------------------------- heads (f32, reversed c) + anchors + proposals
// Decode from CLIPPED anchors (jnp-literal; R8 disproved unclipped).
__global__ __launch_bounds__(256) void heads_kernel(
    const float* __restrict__ y,
    const float* __restrict__ det_w, const float* __restrict__ det_b,
    const float* __restrict__ reg_w, const float* __restrict__ reg_b,
    float* __restrict__ out, double* __restrict__ props,
    double* __restrict__ lgm) {
  const int p = blockIdx.x * 256 + threadIdx.x;
  float od0 = 0.f, od1 = 0.f, od2 = 0.f;
  float rg[12];
#pragma unroll
  for (int o = 0; o < 12; ++o) rg[o] = 0.f;
  const float* yp = y + p;
  for (int c = 255; c >= 0; --c) {      // reversed accumulation
    float v = yp[(size_t)c * NPIX];
    od0 = fmaf(v, det_w[c], od0);
    od1 = fmaf(v, det_w[256 + c], od1);
    od2 = fmaf(v, det_w[512 + c], od2);
#pragma unroll
    for (int o = 0; o < 12; ++o) rg[o] = fmaf(v, reg_w[o * 256 + c], rg[o]);
  }
  const int hh = p / 160;
  const int ww = p - hh * 160;
  const float sx = ww * 4.0f, sy = hh * 4.0f;
  float odv[3] = {od0, od1, od2};
#pragma unroll
  for (int a = 0; a < 3; ++a) {
    float ar = (a == 0) ? 0.5f : ((a == 1) ? 1.0f : 2.0f);
    float sq = sqrtf(ar);
    float haf = 64.0f * sq, waf = 64.0f / sq;
    float ax1 = fminf(fmaxf(sx - waf * 0.5f, 0.f), 640.f);
    float ay1 = fminf(fmaxf(sy - haf * 0.5f, 0.f), 640.f);
    float ax2 = fminf(fmaxf(sx + waf * 0.5f, 0.f), 640.f);
    float ay2 = fminf(fmaxf(sy + haf * 0.5f, 0.f), 640.f);
    int ai = a * NPIX + p;
    out[OUT_ANCH + ai * 4 + 0] = ax1;
    out[OUT_ANCH + ai * 4 + 1] = ay1;
    out[OUT_ANCH + ai * 4 + 2] = ax2;
    out[OUT_ANCH + ai * 4 + 3] = ay2;
    float logit = odv[a] + det_b[a];
    out[OUT_OBJ + ai] = logit;
    float dx = rg[0 + a] + reg_b[0 + a];
    float dy = rg[3 + a] + reg_b[3 + a];
    float dw = rg[6 + a] + reg_b[6 + a];
    float dh = rg[9 + a] + reg_b[9 + a];
    out[OUT_DELT + ai * 4 + 0] = dx;
    out[OUT_DELT + ai * 4 + 1] = dy;
    out[OUT_DELT + ai * 4 + 2] = dw;
    out[OUT_DELT + ai * 4 + 3] = dh;
    // decode from CLIPPED anchor, all f32 (mirrors an f32 reference)
    float aw = ax2 - ax1, ah = ay2 - ay1;
    float cx = ax1 + 0.5f * aw, cy = ay1 + 0.5f * ah;
    float pcx = dx * aw + cx, pcy = dy * ah + cy;
    float pw = aw * expf(dw), ph = ah * expf(dh);
    props[ai * 4 + 0] = (double)fminf(fmaxf(pcx - 0.5f * pw, 0.f), 640.f);
    props[ai * 4 + 1] = (double)fminf(fmaxf(pcy - 0.5f * ph, 0.f), 640.f);
    props[ai * 4 + 2] = (double)fminf(fmaxf(pcx + 0.5f * pw, 0.f), 640.f);
    props[ai * 4 + 3] = (double)fminf(fmaxf(pcy + 0.5f * ph, 0.f), 640.f);
    lgm[ai] = (logit > 0.f) ? (double)logit : -1e9;   // sigmoid>0.5 <=> logit>0
  }
}

// ---------------------------------------------------------------- exact-rank top-2000 (brute force, stable)
__global__ __launch_bounds__(256) void rank_select(const double* __restrict__ lgm,
                                                   const double* __restrict__ props,
                                                   double* __restrict__ tsc,
                                                   double* __restrict__ tbox) {
  __shared__ double ch[1024];
  const int i = blockIdx.x * 256 + threadIdx.x;   // 300 blocks * 256 = 76800 exactly
  const double vi = lgm[i];
  int rank = 0;
  for (int c0 = 0; c0 < NANCH; c0 += 1024) {
    __syncthreads();
    for (int t = threadIdx.x; t < 1024; t += 256) ch[t] = lgm[c0 + t];
    __syncthreads();
#pragma unroll 8
    for (int j = 0; j < 1024; ++j) {
      double vj = ch[j];
      rank += (vj > vi || (vj == vi && (c0 + j) < i)) ? 1 : 0;
    }
  }
  if (rank < 2000) {
    tsc[rank] = vi;
    tbox[rank * 4 + 0] = props[(size_t)i * 4 + 0];
    tbox[rank * 4 + 1] = props[(size_t)i * 4 + 1];
    tbox[rank * 4 + 2] = props[(size_t)i * 4 + 2];
    tbox[rank * 4 + 3] = props[(size_t)i * 4 + 3];
  }
}

// ---------------------------------------------------------------- greedy NMS: literal fori_loop transliteration
__global__ __launch_bounds__(1024) void nms_kernel(const double* __restrict__ tsc,
                                                   const double* __restrict__ tbox,
                                                   float* __restrict__ out) {
  __shared__ double bx[2000][4];     // 64,000 B
  __shared__ unsigned kw[64];        // keep bitmask
  __shared__ unsigned wpfx[65];
  const int tid = threadIdx.x;
  for (int idx = tid; idx < 8000; idx += 1024) bx[idx >> 2][idx & 3] = tbox[idx];
  if (tid < 64) kw[tid] = 0u;
  __syncthreads();
  for (int i = tid; i < 2000; i += 1024)
    if (tsc[i] > -5e8) atomicOr(&kw[i >> 5], 1u << (i & 31));   // valid = top_scores > NEG/2
  __syncthreads();

  for (int i = 0; i < 2000; ++i) {
    bool ki = (kw[i >> 5] >> (i & 31)) & 1u;
    if (ki) {
      double bix = bx[i][0], biy = bx[i][1], biz = bx[i][2], biw = bx[i][3];
      double areai = (biz - bix) * (biw - biy);
      for (int j = i + 1 + tid; j < 2000; j += 1024) {
        if ((kw[j >> 5] >> (j & 31)) & 1u) {
          double xx1 = fmax(bix, bx[j][0]), yy1 = fmax(biy, bx[j][1]);
          double xx2 = fmin(biz, bx[j][2]), yy2 = fmin(biw, bx[j][3]);
          double iw = fmax(xx2 - xx1, 0.0), ih = fmax(yy2 - yy1, 0.0);
          double inter = iw * ih;
          double areaj = (bx[j][2] - bx[j][0]) * (bx[j][3] - bx[j][1]);
          double iou = inter / (areai + areaj - inter + 1e-9);
          if (iou > 0.7) atomicAnd(&kw[j >> 5], ~(1u << (j & 31)));
        }
      }
    }
    __syncthreads();
  }

  if (tid == 0) {
    wpfx[0] = 0;
    for (int w = 0; w < 64; ++w) wpfx[w + 1] = wpfx[w] + __popc(kw[w]);
  }
  __syncthreads();
  for (int i = tid; i < 2000; i += 1024) {
    if ((kw[i >> 5] >> (i & 31)) & 1u) {
      int r = (int)wpfx[i >> 5] + __popc(kw[i >> 5] & ((1u << (i & 31)) - 1u));
      if (r < 1000) {
        out[OUT_FL + r] = (float)tsc[i];
        out[OUT_FB + r * 4 + 0] = (float)bx[i][0];
        out[OUT_FB + r * 4 + 1] = (float)bx[i][1];
        out[OUT_FB + r * 4 + 2] = (float)bx[i][2];
        out[OUT_FB + r * 4 + 3] = (float)bx[i][3];
      }
    }
  }
}

// ---------------------------------------------------------------- launch
extern "C" void kernel_launch(void* const* d_in, const int* in_sizes, int n_in,
                              void* d_out, int out_size, void* d_ws, size_t ws_size,
                              hipStream_t stream) {
  (void)in_sizes; (void)n_in; (void)out_size; (void)ws_size;
  const float* x      = (const float*)d_in[0];
  const float* conv_w = (const float*)d_in[1];
  const float* conv_b = (const float*)d_in[2];
  const float* gamma  = (const float*)d_in[3];
  const float* beta   = (const float*)d_in[4];
  const float* mean   = (const float*)d_in[5];
  const float* var    = (const float*)d_in[6];
  const float* det_w  = (const float*)d_in[7];
  const float* det_b  = (const float*)d_in[8];
  const float* reg_w  = (const float*)d_in[9];
  const float* reg_b  = (const float*)d_in[10];
  float* out = (float*)d_out;
  char* ws = (char*)d_ws;

  float*  y      = (float*)(ws + Y_OFF);
  double* props  = (double*)(ws + PROPS_OFF);
  double* lgm    = (double*)(ws + LGM_OFF);
  double* tsc    = (double*)(ws + TSC_OFF);
  double* tbox   = (double*)(ws + TBOX_OFF);

  init_misc<<<16, 256, 0, stream>>>(out);
  conv_naive_f32r<<<dim3(100, 256), 256, 0, stream>>>(x, conv_w, conv_b, gamma, beta, mean, var, y);
  heads_kernel<<<100, 256, 0, stream>>>(y, det_w, det_b, reg_w, reg_b, out, props, lgm);
  rank_select<<<300, 256, 0, stream>>>(lgm, props, tsc, tbox);
  nms_kernel<<<1, 1024, 0, stream>>>(tsc, tbox, out);
}

// Round 10
// 4628.282 us; speedup vs baseline: 2.8493x; 2.8493x over previous
//
#include <hip/hip_runtime.h>
#include <math.h>

#define NPIX  25600      // 160*160
#define NANCH 76800      // 3*NPIX

// output layout (float elements)
constexpr int OUT_ANCH = 0;        // 76800*4
constexpr int OUT_OBJ  = 307200;   // 76800
constexpr int OUT_DELT = 384000;   // 76800*4
constexpr int OUT_FL   = 691200;   // 1000
constexpr int OUT_FB   = 692200;   // 1000*4

// workspace layout (bytes)
constexpr size_t Y_OFF     = 0;                        // 256*25600*4 = 26,214,400 (f32)
constexpr size_t PROPS_OFF = 26214400;                 // 76800*4*8 = 2,457,600
constexpr size_t KEYF_OFF  = PROPS_OFF + 2457600;      // 76800*4
constexpr size_t TSC_OFF   = KEYF_OFF + 307200;        // 2000*4 -> 8192
constexpr size_t TBOX_OFF  = TSC_OFF + 8192;           // 2000*4*8 -> 65536

// ---------------------------------------------------------------- init
__global__ __launch_bounds__(256) void init_misc(float* __restrict__ out) {
  int t = blockIdx.x * 256 + threadIdx.x;
  if (t < 1000) out[OUT_FL + t] = -1e9f;
  if (t < 4000) out[OUT_FB + t] = 0.f;
}

// ---------------------------------------------------------------- LDS-tiled conv + bn + relu
// NUMERICS FROZEN (R9 pass): per-output fmaf chain must be ic 255->0, taps 8->0.
// Tiling: cb 248->0 step -8, ci 7->0 keeps ic strictly descending; taps r8..r0.
// Zero-padded halo: fmaf(0,w,acc)==acc bit-exact (acc init +0), same as skipping.
__global__ __launch_bounds__(256) void conv_tiled_f32r(
    const float* __restrict__ x, const float* __restrict__ w,
    const float* __restrict__ bv, const float* __restrict__ gamma,
    const float* __restrict__ beta, const float* __restrict__ mean,
    const float* __restrict__ var, float* __restrict__ y) {
  const int tile = blockIdx.x;
  const int th0 = (tile / 10) * 16;
  const int tw0 = (tile - (tile / 10) * 10) * 16;
  const int ob  = blockIdx.y * 16;
  const int tid = threadIdx.x;
  const int tx = tid & 15, ty = tid >> 4;

  __shared__ float lds[8][18][18];

  float acc[16];
#pragma unroll
  for (int i = 0; i < 16; ++i) acc[i] = 0.f;

  for (int cb = 248; cb >= 0; cb -= 8) {       // ic blocks DESCENDING
    __syncthreads();
    for (int idx = tid; idx < 8 * 324; idx += 256) {
      int ci  = idx / 324;
      int rem = idx - ci * 324;
      int r   = rem / 18;
      int cc  = rem - r * 18;
      int gh = th0 + r - 1, gw = tw0 + cc - 1;
      float v = 0.f;
      if ((unsigned)gh < 160u && (unsigned)gw < 160u)
        v = x[(size_t)(cb + ci) * NPIX + gh * 160 + gw];
      lds[ci][r][cc] = v;
    }
    __syncthreads();
#pragma unroll
    for (int ci = 7; ci >= 0; --ci) {          // ic DESCENDING within block
      float r0 = lds[ci][ty    ][tx], r1 = lds[ci][ty    ][tx + 1], r2 = lds[ci][ty    ][tx + 2];
      float r3 = lds[ci][ty + 1][tx], r4 = lds[ci][ty + 1][tx + 1], r5 = lds[ci][ty + 1][tx + 2];
      float r6 = lds[ci][ty + 2][tx], r7 = lds[ci][ty + 2][tx + 1], r8 = lds[ci][ty + 2][tx + 2];
      const float* wp = w + (size_t)ob * 2304 + (size_t)(cb + ci) * 9;
#pragma unroll
      for (int o = 0; o < 16; ++o) {
        const float* wo = wp + (size_t)o * 2304;   // wave-uniform -> scalar loads
        float a = acc[o];
        a = fmaf(r8, wo[8], a); a = fmaf(r7, wo[7], a); a = fmaf(r6, wo[6], a);  // taps 8..6
        a = fmaf(r5, wo[5], a); a = fmaf(r4, wo[4], a); a = fmaf(r3, wo[3], a);  // taps 5..3
        a = fmaf(r2, wo[2], a); a = fmaf(r1, wo[1], a); a = fmaf(r0, wo[0], a);  // taps 2..0
        acc[o] = a;
      }
    }
  }
  const int h = th0 + ty, wv = tw0 + tx;
#pragma unroll
  for (int o = 0; o < 16; ++o) {
    int oc = ob + o;
    float sc = gamma[oc] / sqrtf(var[oc] + 1e-5f);     // epilogue verbatim from R9
    float sh = (bv[oc] - mean[oc]) * sc + beta[oc];
    float v = fmaf(acc[o], sc, sh);
    y[(size_t)oc * NPIX + h * 160 + wv] = (v > 0.f) ? v : 0.f;
  }
}

// ---------------------------------------------------------------- heads (f32, reversed c) + anchors + proposals
// NUMERICS FROZEN (R9 pass): c 255->0, clipped-anchor decode, f32 throughout.
__global__ __launch_bounds__(256) void heads_kernel(
    const float* __restrict__ y,
    const float* __restrict__ det_w, const float* __restrict__ det_b,
    const float* __restrict__ reg_w, const float* __restrict__ reg_b,
    float* __restrict__ out, double* __restrict__ props,
    float* __restrict__ keyf) {
  const int p = blockIdx.x * 256 + threadIdx.x;
  float od0 = 0.f, od1 = 0.f, od2 = 0.f;
  float rg[12];
#pragma unroll
  for (int o = 0; o < 12; ++o) rg[o] = 0.f;
  const float* yp = y + p;
  for (int c = 255; c >= 0; --c) {      // reversed accumulation
    float v = yp[(size_t)c * NPIX];
    od0 = fmaf(v, det_w[c], od0);
    od1 = fmaf(v, det_w[256 + c], od1);
    od2 = fmaf(v, det_w[512 + c], od2);
#pragma unroll
    for (int o = 0; o < 12; ++o) rg[o] = fmaf(v, reg_w[o * 256 + c], rg[o]);
  }
  const int hh = p / 160;
  const int ww = p - hh * 160;
  const float sx = ww * 4.0f, sy = hh * 4.0f;
  float odv[3] = {od0, od1, od2};
#pragma unroll
  for (int a = 0; a < 3; ++a) {
    float ar = (a == 0) ? 0.5f : ((a == 1) ? 1.0f : 2.0f);
    float sq = sqrtf(ar);
    float haf = 64.0f * sq, waf = 64.0f / sq;
    float ax1 = fminf(fmaxf(sx - waf * 0.5f, 0.f), 640.f);
    float ay1 = fminf(fmaxf(sy - haf * 0.5f, 0.f), 640.f);
    float ax2 = fminf(fmaxf(sx + waf * 0.5f, 0.f), 640.f);
    float ay2 = fminf(fmaxf(sy + haf * 0.5f, 0.f), 640.f);
    int ai = a * NPIX + p;
    out[OUT_ANCH + ai * 4 + 0] = ax1;
    out[OUT_ANCH + ai * 4 + 1] = ay1;
    out[OUT_ANCH + ai * 4 + 2] = ax2;
    out[OUT_ANCH + ai * 4 + 3] = ay2;
    float logit = odv[a] + det_b[a];
    out[OUT_OBJ + ai] = logit;
    float dx = rg[0 + a] + reg_b[0 + a];
    float dy = rg[3 + a] + reg_b[3 + a];
    float dw = rg[6 + a] + reg_b[6 + a];
    float dh = rg[9 + a] + reg_b[9 + a];
    out[OUT_DELT + ai * 4 + 0] = dx;
    out[OUT_DELT + ai * 4 + 1] = dy;
    out[OUT_DELT + ai * 4 + 2] = dw;
    out[OUT_DELT + ai * 4 + 3] = dh;
    float aw = ax2 - ax1, ah = ay2 - ay1;
    float cx = ax1 + 0.5f * aw, cy = ay1 + 0.5f * ah;
    float pcx = dx * aw + cx, pcy = dy * ah + cy;
    float pw = aw * expf(dw), ph = ah * expf(dh);
    props[ai * 4 + 0] = (double)fminf(fmaxf(pcx - 0.5f * pw, 0.f), 640.f);
    props[ai * 4 + 1] = (double)fminf(fmaxf(pcy - 0.5f * ph, 0.f), 640.f);
    props[ai * 4 + 2] = (double)fminf(fmaxf(pcx + 0.5f * pw, 0.f), 640.f);
    props[ai * 4 + 3] = (double)fminf(fmaxf(pcy + 0.5f * ph, 0.f), 640.f);
    // f32 key: f64 embedding of f32 is injective & order-preserving, and
    // -1e9f == -1e9 exactly -> decisions bit-identical to R9's f64 keys.
    keyf[ai] = (logit > 0.f) ? logit : -1e9f;
  }
}

// ---------------------------------------------------------------- exact-rank top-2000 (brute force, stable, f32 keys)
__global__ __launch_bounds__(256) void rank_select(const float* __restrict__ keyf,
                                                   const double* __restrict__ props,
                                                   float* __restrict__ tsc,
                                                   double* __restrict__ tbox) {
  __shared__ float ch[1024];
  const int i = blockIdx.x * 256 + threadIdx.x;   // 300 blocks * 256 = 76800 exactly
  const float vi = keyf[i];
  int rank = 0;
  for (int c0 = 0; c0 < NANCH; c0 += 1024) {
    __syncthreads();
    for (int t = threadIdx.x; t < 1024; t += 256) ch[t] = keyf[c0 + t];
    __syncthreads();
#pragma unroll 8
    for (int j = 0; j < 1024; ++j) {
      float vj = ch[j];
      rank += (vj > vi || (vj == vi && (c0 + j) < i)) ? 1 : 0;
    }
  }
  if (rank < 2000) {
    tsc[rank] = vi;
    tbox[rank * 4 + 0] = props[(size_t)i * 4 + 0];
    tbox[rank * 4 + 1] = props[(size_t)i * 4 + 1];
    tbox[rank * 4 + 2] = props[(size_t)i * 4 + 2];
    tbox[rank * 4 + 3] = props[(size_t)i * 4 + 3];
  }
}

// ---------------------------------------------------------------- greedy NMS: literal fori_loop transliteration (f64, frozen)
__global__ __launch_bounds__(1024) void nms_kernel(const float* __restrict__ tsc,
                                                   const double* __restrict__ tbox,
                                                   float* __restrict__ out) {
  __shared__ double bx[2000][4];     // 64,000 B
  __shared__ unsigned kw[64];        // keep bitmask
  __shared__ unsigned wpfx[65];
  const int tid = threadIdx.x;
  for (int idx = tid; idx < 8000; idx += 1024) bx[idx >> 2][idx & 3] = tbox[idx];
  if (tid < 64) kw[tid] = 0u;
  __syncthreads();
  for (int i = tid; i < 2000; i += 1024)
    if (tsc[i] > -5e8f) atomicOr(&kw[i >> 5], 1u << (i & 31));   // valid = top_scores > NEG/2
  __syncthreads();

  for (int i = 0; i < 2000; ++i) {
    bool ki = (kw[i >> 5] >> (i & 31)) & 1u;
    if (ki) {
      double bix = bx[i][0], biy = bx[i][1], biz = bx[i][2], biw = bx[i][3];
      double areai = (biz - bix) * (biw - biy);
      for (int j = i + 1 + tid; j < 2000; j += 1024) {
        if ((kw[j >> 5] >> (j & 31)) & 1u) {
          double xx1 = fmax(bix, bx[j][0]), yy1 = fmax(biy, bx[j][1]);
          double xx2 = fmin(biz, bx[j][2]), yy2 = fmin(biw, bx[j][3]);
          double iw = fmax(xx2 - xx1, 0.0), ih = fmax(yy2 - yy1, 0.0);
          double inter = iw * ih;
          double areaj = (bx[j][2] - bx[j][0]) * (bx[j][3] - bx[j][1]);
          double iou = inter / (areai + areaj - inter + 1e-9);
          if (iou > 0.7) atomicAnd(&kw[j >> 5], ~(1u << (j & 31)));
        }
      }
    }
    __syncthreads();
  }

  if (tid == 0) {
    wpfx[0] = 0;
    for (int w = 0; w < 64; ++w) wpfx[w + 1] = wpfx[w] + __popc(kw[w]);
  }
  __syncthreads();
  for (int i = tid; i < 2000; i += 1024) {
    if ((kw[i >> 5] >> (i & 31)) & 1u) {
      int r = (int)wpfx[i >> 5] + __popc(kw[i >> 5] & ((1u << (i & 31)) - 1u));
      if (r < 1000) {
        out[OUT_FL + r] = tsc[i];
        out[OUT_FB + r * 4 + 0] = (float)bx[i][0];
        out[OUT_FB + r * 4 + 1] = (float)bx[i][1];
        out[OUT_FB + r * 4 + 2] = (float)bx[i][2];
        out[OUT_FB + r * 4 + 3] = (float)bx[i][3];
      }
    }
  }
}

// ---------------------------------------------------------------- launch
extern "C" void kernel_launch(void* const* d_in, const int* in_sizes, int n_in,
                              void* d_out, int out_size, void* d_ws, size_t ws_size,
                              hipStream_t stream) {
  (void)in_sizes; (void)n_in; (void)out_size; (void)ws_size;
  const float* x      = (const float*)d_in[0];
  const float* conv_w = (const float*)d_in[1];
  const float* conv_b = (const float*)d_in[2];
  const float* gamma  = (const float*)d_in[3];
  const float* beta   = (const float*)d_in[4];
  const float* mean   = (const float*)d_in[5];
  const float* var    = (const float*)d_in[6];
  const float* det_w  = (const float*)d_in[7];
  const float* det_b  = (const float*)d_in[8];
  const float* reg_w  = (const float*)d_in[9];
  const float* reg_b  = (const float*)d_in[10];
  float* out = (float*)d_out;
  char* ws = (char*)d_ws;

  float*  y      = (float*)(ws + Y_OFF);
  double* props  = (double*)(ws + PROPS_OFF);
  float*  keyf   = (float*)(ws + KEYF_OFF);
  float*  tsc    = (float*)(ws + TSC_OFF);
  double* tbox   = (double*)(ws + TBOX_OFF);

  init_misc<<<16, 256, 0, stream>>>(out);
  conv_tiled_f32r<<<dim3(100, 16), 256, 0, stream>>>(x, conv_w, conv_b, gamma, beta, mean, var, y);
  heads_kernel<<<100, 256, 0, stream>>>(y, det_w, det_b, reg_w, reg_b, out, props, keyf);
  rank_select<<<300, 256, 0, stream>>>(keyf, props, tsc, tbox);
  nms_kernel<<<1, 1024, 0, stream>>>(tsc, tbox, out);
}

// Round 11
// 2124.183 us; speedup vs baseline: 6.2082x; 2.1789x over previous
//
#include <hip/hip_runtime.h>
#include <math.h>

#define NPIX  25600      // 160*160
#define NANCH 76800      // 3*NPIX

// output layout (float elements)
constexpr int OUT_ANCH = 0;        // 76800*4
constexpr int OUT_OBJ  = 307200;   // 76800
constexpr int OUT_DELT = 384000;   // 76800*4
constexpr int OUT_FL   = 691200;   // 1000
constexpr int OUT_FB   = 692200;   // 1000*4

// workspace layout (bytes)
constexpr size_t Y_OFF     = 0;                        // 26,214,400 (f32)
constexpr size_t PROPS_OFF = 26214400;                 // 76800*4*8
constexpr size_t KEYF_OFF  = PROPS_OFF + 2457600;      // 76800*4
constexpr size_t CANDK_OFF = KEYF_OFF + 307200;        // 4096*4
constexpr size_t CANDI_OFF = CANDK_OFF + 16384;        // 4096*4
constexpr size_t TSC_OFF   = CANDI_OFF + 16384;        // 2000*4 -> 8192
constexpr size_t TBOX_OFF  = TSC_OFF + 8192;           // 2000*4*8 -> 65536
constexpr size_t HIST_OFF  = TBOX_OFF + 65536;         // 256*4 -> 1024
constexpr size_t STATE_OFF = HIST_OFF + 1024;

struct SelState { unsigned prefix; int remaining; int cntHi; int cntEq; };

__device__ __forceinline__ unsigned orderKey32(float f) {
  unsigned u = __float_as_uint(f);
  return (u & 0x80000000u) ? ~u : (u | 0x80000000u);
}
__device__ __forceinline__ float key32ToFloat(unsigned k) {
  unsigned u = (k & 0x80000000u) ? (k & 0x7fffffffu) : ~k;
  return __uint_as_float(u);
}

// ---------------------------------------------------------------- init
__global__ __launch_bounds__(256) void init_misc(float* __restrict__ out,
                                                 unsigned* __restrict__ hist,
                                                 SelState* __restrict__ st) {
  int t = blockIdx.x * 256 + threadIdx.x;
  if (t < 1000) out[OUT_FL + t] = -1e9f;
  if (t < 4000) out[OUT_FB + t] = 0.f;
  if (t < 256) hist[t] = 0u;
  if (t == 0) { st->prefix = 0u; st->remaining = 2000; st->cntHi = 0; st->cntEq = 0; }
}

// ---------------------------------------------------------------- LDS-tiled conv + bn + relu, software-pipelined staging
// NUMERICS FROZEN (R9/R10 pass): per-output fmaf chain ic 255->0, taps 8->0.
// Pipeline: global loads for cb-8 issued BEFORE compute of cb (vmcnt hides
// under the 1152-fmaf body); ds_write after barrier. Same values -> same cells
// -> bit-identical y.
__global__ __launch_bounds__(256) void conv_tiled_f32r(
    const float* __restrict__ x, const float* __restrict__ w,
    const float* __restrict__ bv, const float* __restrict__ gamma,
    const float* __restrict__ beta, const float* __restrict__ mean,
    const float* __restrict__ var, float* __restrict__ y) {
  const int tile = blockIdx.x;
  const int th0 = (tile / 10) * 16;
  const int tw0 = (tile - (tile / 10) * 10) * 16;
  const int ob  = blockIdx.y * 16;
  const int tid = threadIdx.x;
  const int tx = tid & 15, ty = tid >> 4;

  __shared__ float lds[8][18][18];   // 2592 floats

  float sreg[11];                    // 11*256 = 2816 >= 2592
  auto loadRegs = [&](int cb) {
#pragma unroll
    for (int k = 0; k < 11; ++k) {
      int idx = tid + k * 256;
      float v = 0.f;
      if (idx < 2592) {
        int ci = idx / 324; int rem = idx - ci * 324;
        int r = rem / 18;   int cc = rem - r * 18;
        int gh = th0 + r - 1, gw = tw0 + cc - 1;
        if ((unsigned)gh < 160u && (unsigned)gw < 160u)
          v = x[(size_t)(cb + ci) * NPIX + gh * 160 + gw];
      }
      sreg[k] = v;
    }
  };
  auto writeRegs = [&]() {
#pragma unroll
    for (int k = 0; k < 11; ++k) {
      int idx = tid + k * 256;
      if (idx < 2592) ((float*)lds)[idx] = sreg[k];
    }
  };

  float acc[16];
#pragma unroll
  for (int i = 0; i < 16; ++i) acc[i] = 0.f;

  loadRegs(248);
  for (int cb = 248; cb >= 0; cb -= 8) {       // ic blocks DESCENDING
    __syncthreads();                           // prior compute done reading lds
    writeRegs();
    __syncthreads();                           // staging visible
    if (cb > 0) loadRegs(cb - 8);              // prefetch next chunk (vmcnt pending)
#pragma unroll
    for (int ci = 7; ci >= 0; --ci) {          // ic DESCENDING within block
      float r0 = lds[ci][ty    ][tx], r1 = lds[ci][ty    ][tx + 1], r2 = lds[ci][ty    ][tx + 2];
      float r3 = lds[ci][ty + 1][tx], r4 = lds[ci][ty + 1][tx + 1], r5 = lds[ci][ty + 1][tx + 2];
      float r6 = lds[ci][ty + 2][tx], r7 = lds[ci][ty + 2][tx + 1], r8 = lds[ci][ty + 2][tx + 2];
      const float* wp = w + (size_t)ob * 2304 + (size_t)(cb + ci) * 9;
#pragma unroll
      for (int o = 0; o < 16; ++o) {
        const float* wo = wp + (size_t)o * 2304;   // wave-uniform -> scalar loads
        float a = acc[o];
        a = fmaf(r8, wo[8], a); a = fmaf(r7, wo[7], a); a = fmaf(r6, wo[6], a);  // taps 8..6
        a = fmaf(r5, wo[5], a); a = fmaf(r4, wo[4], a); a = fmaf(r3, wo[3], a);  // taps 5..3
        a = fmaf(r2, wo[2], a); a = fmaf(r1, wo[1], a); a = fmaf(r0, wo[0], a);  // taps 2..0
        acc[o] = a;
      }
    }
  }
  const int h = th0 + ty, wv = tw0 + tx;
#pragma unroll
  for (int o = 0; o < 16; ++o) {
    int oc = ob + o;
    float sc = gamma[oc] / sqrtf(var[oc] + 1e-5f);     // epilogue verbatim
    float sh = (bv[oc] - mean[oc]) * sc + beta[oc];
    float v = fmaf(acc[o], sc, sh);
    y[(size_t)oc * NPIX + h * 160 + wv] = (v > 0.f) ? v : 0.f;
  }
}

// ---------------------------------------------------------------- heads (f32, reversed c) + anchors + proposals
// NUMERICS FROZEN (R9 pass): c 255->0, clipped-anchor decode, f32 throughout.
__global__ __launch_bounds__(256) void heads_kernel(
    const float* __restrict__ y,
    const float* __restrict__ det_w, const float* __restrict__ det_b,
    const float* __restrict__ reg_w, const float* __restrict__ reg_b,
    float* __restrict__ out, double* __restrict__ props,
    float* __restrict__ keyf) {
  const int p = blockIdx.x * 256 + threadIdx.x;
  float od0 = 0.f, od1 = 0.f, od2 = 0.f;
  float rg[12];
#pragma unroll
  for (int o = 0; o < 12; ++o) rg[o] = 0.f;
  const float* yp = y + p;
  for (int c = 255; c >= 0; --c) {      // reversed accumulation
    float v = yp[(size_t)c * NPIX];
    od0 = fmaf(v, det_w[c], od0);
    od1 = fmaf(v, det_w[256 + c], od1);
    od2 = fmaf(v, det_w[512 + c], od2);
#pragma unroll
    for (int o = 0; o < 12; ++o) rg[o] = fmaf(v, reg_w[o * 256 + c], rg[o]);
  }
  const int hh = p / 160;
  const int ww = p - hh * 160;
  const float sx = ww * 4.0f, sy = hh * 4.0f;
  float odv[3] = {od0, od1, od2};
#pragma unroll
  for (int a = 0; a < 3; ++a) {
    float ar = (a == 0) ? 0.5f : ((a == 1) ? 1.0f : 2.0f);
    float sq = sqrtf(ar);
    float haf = 64.0f * sq, waf = 64.0f / sq;
    float ax1 = fminf(fmaxf(sx - waf * 0.5f, 0.f), 640.f);
    float ay1 = fminf(fmaxf(sy - haf * 0.5f, 0.f), 640.f);
    float ax2 = fminf(fmaxf(sx + waf * 0.5f, 0.f), 640.f);
    float ay2 = fminf(fmaxf(sy + haf * 0.5f, 0.f), 640.f);
    int ai = a * NPIX + p;
    out[OUT_ANCH + ai * 4 + 0] = ax1;
    out[OUT_ANCH + ai * 4 + 1] = ay1;
    out[OUT_ANCH + ai * 4 + 2] = ax2;
    out[OUT_ANCH + ai * 4 + 3] = ay2;
    float logit = odv[a] + det_b[a];
    out[OUT_OBJ + ai] = logit;
    float dx = rg[0 + a] + reg_b[0 + a];
    float dy = rg[3 + a] + reg_b[3 + a];
    float dw = rg[6 + a] + reg_b[6 + a];
    float dh = rg[9 + a] + reg_b[9 + a];
    out[OUT_DELT + ai * 4 + 0] = dx;
    out[OUT_DELT + ai * 4 + 1] = dy;
    out[OUT_DELT + ai * 4 + 2] = dw;
    out[OUT_DELT + ai * 4 + 3] = dh;
    float aw = ax2 - ax1, ah = ay2 - ay1;
    float cx = ax1 + 0.5f * aw, cy = ay1 + 0.5f * ah;
    float pcx = dx * aw + cx, pcy = dy * ah + cy;
    float pw = aw * expf(dw), ph = ah * expf(dh);
    props[ai * 4 + 0] = (double)fminf(fmaxf(pcx - 0.5f * pw, 0.f), 640.f);
    props[ai * 4 + 1] = (double)fminf(fmaxf(pcy - 0.5f * ph, 0.f), 640.f);
    props[ai * 4 + 2] = (double)fminf(fmaxf(pcx + 0.5f * pw, 0.f), 640.f);
    props[ai * 4 + 3] = (double)fminf(fmaxf(pcy + 0.5f * ph, 0.f), 640.f);
    keyf[ai] = (logit > 0.f) ? logit : -1e9f;   // sigmoid>0.5 <=> logit>0
  }
}

// ---------------------------------------------------------------- radix select (4 x 8-bit, MSB first) on 32-bit order keys
// After 4 passes st->prefix = exact order-key of the 2000th-largest element.
// (R4-proven machinery: matched brute-force rank_select byte-for-byte.)
__global__ __launch_bounds__(256) void hist_pass(const float* __restrict__ keyf,
                                                 unsigned* __restrict__ hist,
                                                 const SelState* __restrict__ st, int pass) {
  __shared__ unsigned lh[256];
  lh[threadIdx.x] = 0u;
  __syncthreads();
  unsigned prefix = st->prefix;
  int shift = 24 - 8 * pass;
  int i = blockIdx.x * 256 + threadIdx.x;   // 300*256 = 76800 exactly
  unsigned k = orderKey32(keyf[i]);
  bool ok = (pass == 0) || ((k >> (shift + 8)) == prefix);
  if (ok) atomicAdd(&lh[(k >> shift) & 255u], 1u);
  __syncthreads();
  unsigned c = lh[threadIdx.x];
  if (c) atomicAdd(&hist[threadIdx.x], c);
}

__global__ void pick_kernel(unsigned* __restrict__ hist, SelState* __restrict__ st) {
  if (threadIdx.x == 0 && blockIdx.x == 0) {
    int rem = st->remaining;
    unsigned cum = 0;
    int b = 0;
    for (int i = 255; i >= 0; --i) {
      unsigned h = hist[i];
      if (cum + h >= (unsigned)rem) { b = i; break; }
      cum += h;
    }
    st->prefix = (st->prefix << 8) | (unsigned)b;
    st->remaining = rem - (int)cum;
    for (int i = 0; i < 256; ++i) hist[i] = 0u;
  }
}

// ---------------------------------------------------------------- compact: k > T in [0,2048), k == T in [2048,4096)
// count(k > T) <= 1999 by radix invariant. eq overflow only possible for the
// -1e9 flood, whose members never reach the output (keep=False in NMS).
__global__ __launch_bounds__(256) void compact_kernel(const float* __restrict__ keyf,
                                                      SelState* __restrict__ st,
                                                      unsigned* __restrict__ candk,
                                                      unsigned* __restrict__ candi) {
  int i = blockIdx.x * 256 + threadIdx.x;
  if (i >= NANCH) return;
  unsigned k = orderKey32(keyf[i]);
  unsigned T = st->prefix;
  if (k > T) {
    int pos = atomicAdd(&st->cntHi, 1);
    if (pos < 2048) { candk[pos] = k; candi[pos] = (unsigned)i; }
  } else if (k == T) {
    int pos = atomicAdd(&st->cntEq, 1);
    if (pos < 2048) { candk[2048 + pos] = k; candi[2048 + pos] = (unsigned)i; }
  }
}

// ---------------------------------------------------------------- bitonic sort 4096 (key desc, idx asc) + gather
__global__ __launch_bounds__(1024) void sort_gather(const unsigned* __restrict__ candk,
                                                    const unsigned* __restrict__ candi,
                                                    const SelState* __restrict__ st,
                                                    const double* __restrict__ props,
                                                    float* __restrict__ tsc,
                                                    double* __restrict__ tbox) {
  __shared__ unsigned ka[4096];
  __shared__ unsigned ia[4096];
  int nHi = st->cntHi; if (nHi > 2048) nHi = 2048;
  int nEq = st->cntEq; if (nEq > 2048) nEq = 2048;
  for (int i = threadIdx.x; i < 4096; i += 1024) {
    bool real = (i < nHi) || (i >= 2048 && i < 2048 + nEq);
    ka[i] = real ? candk[i] : 0u;
    ia[i] = real ? candi[i] : 0xffffffffu;
  }
  __syncthreads();
  for (int k = 2; k <= 4096; k <<= 1) {
    for (int j = k >> 1; j > 0; j >>= 1) {
      for (int e = threadIdx.x; e < 4096; e += 1024) {
        int l = e ^ j;
        if (l > e) {
          unsigned ke = ka[e], kl = ka[l];
          unsigned ie = ia[e], il = ia[l];
          bool descending = ((e & k) == 0);
          bool lBetter = (kl > ke) || (kl == ke && il < ie);
          bool eBetter = (ke > kl) || (ke == kl && ie < il);
          bool sw = descending ? lBetter : eBetter;
          if (sw) { ka[e] = kl; ka[l] = ke; ia[e] = il; ia[l] = ie; }
        }
      }
      __syncthreads();
    }
  }
  for (int t = threadIdx.x; t < 2000; t += 1024) {
    unsigned idx = ia[t];
    if (idx < (unsigned)NANCH) {
      tsc[t] = key32ToFloat(ka[t]);
      tbox[t * 4 + 0] = props[(size_t)idx * 4 + 0];
      tbox[t * 4 + 1] = props[(size_t)idx * 4 + 1];
      tbox[t * 4 + 2] = props[(size_t)idx * 4 + 2];
      tbox[t * 4 + 3] = props[(size_t)idx * 4 + 3];
    } else {
      tsc[t] = -1e9f;     // invalid: never kept, never output
      tbox[t * 4 + 0] = 0.0; tbox[t * 4 + 1] = 0.0;
      tbox[t * 4 + 2] = 0.0; tbox[t * 4 + 3] = 0.0;
    }
  }
}

// ---------------------------------------------------------------- greedy NMS: literal fori_loop transliteration (frozen)
__global__ __launch_bounds__(1024) void nms_kernel(const float* __restrict__ tsc,
                                                   const double* __restrict__ tbox,
                                                   float* __restrict__ out) {
  __shared__ double bx[2000][4];     // 64,000 B
  __shared__ unsigned kw[64];        // keep bitmask
  __shared__ unsigned wpfx[65];
  const int tid = threadIdx.x;
  for (int idx = tid; idx < 8000; idx += 1024) bx[idx >> 2][idx & 3] = tbox[idx];
  if (tid < 64) kw[tid] = 0u;
  __syncthreads();
  for (int i = tid; i < 2000; i += 1024)
    if (tsc[i] > -5e8f) atomicOr(&kw[i >> 5], 1u << (i & 31));   // valid = top_scores > NEG/2
  __syncthreads();

  for (int i = 0; i < 2000; ++i) {
    bool ki = (kw[i >> 5] >> (i & 31)) & 1u;
    if (ki) {
      double bix = bx[i][0], biy = bx[i][1], biz = bx[i][2], biw = bx[i][3];
      double areai = (biz - bix) * (biw - biy);
      for (int j = i + 1 + tid; j < 2000; j += 1024) {
        if ((kw[j >> 5] >> (j & 31)) & 1u) {
          double xx1 = fmax(bix, bx[j][0]), yy1 = fmax(biy, bx[j][1]);
          double xx2 = fmin(biz, bx[j][2]), yy2 = fmin(biw, bx[j][3]);
          double iw = fmax(xx2 - xx1, 0.0), ih = fmax(yy2 - yy1, 0.0);
          double inter = iw * ih;
          double areaj = (bx[j][2] - bx[j][0]) * (bx[j][3] - bx[j][1]);
          double iou = inter / (areai + areaj - inter + 1e-9);
          if (iou > 0.7) atomicAnd(&kw[j >> 5], ~(1u << (j & 31)));
        }
      }
    }
    __syncthreads();
  }

  if (tid == 0) {
    wpfx[0] = 0;
    for (int w = 0; w < 64; ++w) wpfx[w + 1] = wpfx[w] + __popc(kw[w]);
  }
  __syncthreads();
  for (int i = tid; i < 2000; i += 1024) {
    if ((kw[i >> 5] >> (i & 31)) & 1u) {
      int r = (int)wpfx[i >> 5] + __popc(kw[i >> 5] & ((1u << (i & 31)) - 1u));
      if (r < 1000) {
        out[OUT_FL + r] = tsc[i];
        out[OUT_FB + r * 4 + 0] = (float)bx[i][0];
        out[OUT_FB + r * 4 + 1] = (float)bx[i][1];
        out[OUT_FB + r * 4 + 2] = (float)bx[i][2];
        out[OUT_FB + r * 4 + 3] = (float)bx[i][3];
      }
    }
  }
}

// ---------------------------------------------------------------- launch
extern "C" void kernel_launch(void* const* d_in, const int* in_sizes, int n_in,
                              void* d_out, int out_size, void* d_ws, size_t ws_size,
                              hipStream_t stream) {
  (void)in_sizes; (void)n_in; (void)out_size; (void)ws_size;
  const float* x      = (const float*)d_in[0];
  const float* conv_w = (const float*)d_in[1];
  const float* conv_b = (const float*)d_in[2];
  const float* gamma  = (const float*)d_in[3];
  const float* beta   = (const float*)d_in[4];
  const float* mean   = (const float*)d_in[5];
  const float* var    = (const float*)d_in[6];
  const float* det_w  = (const float*)d_in[7];
  const float* det_b  = (const float*)d_in[8];
  const float* reg_w  = (const float*)d_in[9];
  const float* reg_b  = (const float*)d_in[10];
  float* out = (float*)d_out;
  char* ws = (char*)d_ws;

  float*  y      = (float*)(ws + Y_OFF);
  double* props  = (double*)(ws + PROPS_OFF);
  float*  keyf   = (float*)(ws + KEYF_OFF);
  unsigned* candk = (unsigned*)(ws + CANDK_OFF);
  unsigned* candi = (unsigned*)(ws + CANDI_OFF);
  float*  tsc    = (float*)(ws + TSC_OFF);
  double* tbox   = (double*)(ws + TBOX_OFF);
  unsigned* hist = (unsigned*)(ws + HIST_OFF);
  SelState* st   = (SelState*)(ws + STATE_OFF);

  init_misc<<<16, 256, 0, stream>>>(out, hist, st);
  conv_tiled_f32r<<<dim3(100, 16), 256, 0, stream>>>(x, conv_w, conv_b, gamma, beta, mean, var, y);
  heads_kernel<<<100, 256, 0, stream>>>(y, det_w, det_b, reg_w, reg_b, out, props, keyf);
  for (int p = 0; p < 4; ++p) {
    hist_pass<<<300, 256, 0, stream>>>(keyf, hist, st, p);
    pick_kernel<<<1, 64, 0, stream>>>(hist, st);
  }
  compact_kernel<<<300, 256, 0, stream>>>(keyf, st, candk, candi);
  sort_gather<<<1, 1024, 0, stream>>>(candk, candi, st, props, tsc, tbox);
  nms_kernel<<<1, 1024, 0, stream>>>(tsc, tbox, out);
}

// Round 12
// 1653.560 us; speedup vs baseline: 7.9751x; 1.2846x over previous
//
#include <hip/hip_runtime.h>
#include <math.h>

#define NPIX  25600      // 160*160
#define NANCH 76800      // 3*NPIX

// output layout (float elements)
constexpr int OUT_ANCH = 0;        // 76800*4
constexpr int OUT_OBJ  = 307200;   // 76800
constexpr int OUT_DELT = 384000;   // 76800*4
constexpr int OUT_FL   = 691200;   // 1000
constexpr int OUT_FB   = 692200;   // 1000*4

// workspace layout (bytes)
constexpr size_t Y_OFF      = 0;                        // 26,214,400 (f32)
constexpr size_t PROPS_OFF  = 26214400;                 // 76800*4*8
constexpr size_t KEYF_OFF   = PROPS_OFF + 2457600;      // 76800*4
constexpr size_t CANDK_OFF  = KEYF_OFF + 307200;        // 4096*4
constexpr size_t CANDI_OFF  = CANDK_OFF + 16384;        // 4096*4
constexpr size_t TSC_OFF    = CANDI_OFF + 16384;        // 2000*4 -> 8192
constexpr size_t TBOX_OFF   = TSC_OFF + 8192;           // 2000*4*8 -> 65536
constexpr size_t HIST_OFF   = TBOX_OFF + 65536;         // 256*4 -> 1024
constexpr size_t STATE_OFF  = HIST_OFF + 1024;          // -> 256
constexpr size_t MASK32_OFF = STATE_OFF + 256;          // 2000*64*4 = 512000

struct SelState { unsigned prefix; int remaining; int cntHi; int cntEq; };

__device__ __forceinline__ unsigned orderKey32(float f) {
  unsigned u = __float_as_uint(f);
  return (u & 0x80000000u) ? ~u : (u | 0x80000000u);
}
__device__ __forceinline__ float key32ToFloat(unsigned k) {
  unsigned u = (k & 0x80000000u) ? (k & 0x7fffffffu) : ~k;
  return __uint_as_float(u);
}

// ---------------------------------------------------------------- init
__global__ __launch_bounds__(256) void init_misc(float* __restrict__ out,
                                                 unsigned* __restrict__ hist,
                                                 SelState* __restrict__ st) {
  int t = blockIdx.x * 256 + threadIdx.x;
  if (t < 1000) out[OUT_FL + t] = -1e9f;
  if (t < 4000) out[OUT_FB + t] = 0.f;
  if (t < 256) hist[t] = 0u;
  if (t == 0) { st->prefix = 0u; st->remaining = 2000; st->cntHi = 0; st->cntEq = 0; }
}

// ---------------------------------------------------------------- LDS-tiled conv + bn + relu, software-pipelined staging
// NUMERICS FROZEN (R9/R10/R11 pass): per-output fmaf chain ic 255->0, taps 8->0.
__global__ __launch_bounds__(256) void conv_tiled_f32r(
    const float* __restrict__ x, const float* __restrict__ w,
    const float* __restrict__ bv, const float* __restrict__ gamma,
    const float* __restrict__ beta, const float* __restrict__ mean,
    const float* __restrict__ var, float* __restrict__ y) {
  const int tile = blockIdx.x;
  const int th0 = (tile / 10) * 16;
  const int tw0 = (tile - (tile / 10) * 10) * 16;
  const int ob  = blockIdx.y * 16;
  const int tid = threadIdx.x;
  const int tx = tid & 15, ty = tid >> 4;

  __shared__ float lds[8][18][18];   // 2592 floats

  float sreg[11];                    // 11*256 = 2816 >= 2592
  auto loadRegs = [&](int cb) {
#pragma unroll
    for (int k = 0; k < 11; ++k) {
      int idx = tid + k * 256;
      float v = 0.f;
      if (idx < 2592) {
        int ci = idx / 324; int rem = idx - ci * 324;
        int r = rem / 18;   int cc = rem - r * 18;
        int gh = th0 + r - 1, gw = tw0 + cc - 1;
        if ((unsigned)gh < 160u && (unsigned)gw < 160u)
          v = x[(size_t)(cb + ci) * NPIX + gh * 160 + gw];
      }
      sreg[k] = v;
    }
  };
  auto writeRegs = [&]() {
#pragma unroll
    for (int k = 0; k < 11; ++k) {
      int idx = tid + k * 256;
      if (idx < 2592) ((float*)lds)[idx] = sreg[k];
    }
  };

  float acc[16];
#pragma unroll
  for (int i = 0; i < 16; ++i) acc[i] = 0.f;

  loadRegs(248);
  for (int cb = 248; cb >= 0; cb -= 8) {       // ic blocks DESCENDING
    __syncthreads();
    writeRegs();
    __syncthreads();
    if (cb > 0) loadRegs(cb - 8);              // prefetch next chunk
#pragma unroll
    for (int ci = 7; ci >= 0; --ci) {          // ic DESCENDING within block
      float r0 = lds[ci][ty    ][tx], r1 = lds[ci][ty    ][tx + 1], r2 = lds[ci][ty    ][tx + 2];
      float r3 = lds[ci][ty + 1][tx], r4 = lds[ci][ty + 1][tx + 1], r5 = lds[ci][ty + 1][tx + 2];
      float r6 = lds[ci][ty + 2][tx], r7 = lds[ci][ty + 2][tx + 1], r8 = lds[ci][ty + 2][tx + 2];
      const float* wp = w + (size_t)ob * 2304 + (size_t)(cb + ci) * 9;
#pragma unroll
      for (int o = 0; o < 16; ++o) {
        const float* wo = wp + (size_t)o * 2304;   // wave-uniform -> scalar loads
        float a = acc[o];
        a = fmaf(r8, wo[8], a); a = fmaf(r7, wo[7], a); a = fmaf(r6, wo[6], a);
        a = fmaf(r5, wo[5], a); a = fmaf(r4, wo[4], a); a = fmaf(r3, wo[3], a);
        a = fmaf(r2, wo[2], a); a = fmaf(r1, wo[1], a); a = fmaf(r0, wo[0], a);
        acc[o] = a;
      }
    }
  }
  const int h = th0 + ty, wv = tw0 + tx;
#pragma unroll
  for (int o = 0; o < 16; ++o) {
    int oc = ob + o;
    float sc = gamma[oc] / sqrtf(var[oc] + 1e-5f);
    float sh = (bv[oc] - mean[oc]) * sc + beta[oc];
    float v = fmaf(acc[o], sc, sh);
    y[(size_t)oc * NPIX + h * 160 + wv] = (v > 0.f) ? v : 0.f;
  }
}

// ---------------------------------------------------------------- heads (f32, reversed c) + anchors + proposals (FROZEN)
__global__ __launch_bounds__(256) void heads_kernel(
    const float* __restrict__ y,
    const float* __restrict__ det_w, const float* __restrict__ det_b,
    const float* __restrict__ reg_w, const float* __restrict__ reg_b,
    float* __restrict__ out, double* __restrict__ props,
    float* __restrict__ keyf) {
  const int p = blockIdx.x * 256 + threadIdx.x;
  float od0 = 0.f, od1 = 0.f, od2 = 0.f;
  float rg[12];
#pragma unroll
  for (int o = 0; o < 12; ++o) rg[o] = 0.f;
  const float* yp = y + p;
  for (int c = 255; c >= 0; --c) {      // reversed accumulation
    float v = yp[(size_t)c * NPIX];
    od0 = fmaf(v, det_w[c], od0);
    od1 = fmaf(v, det_w[256 + c], od1);
    od2 = fmaf(v, det_w[512 + c], od2);
#pragma unroll
    for (int o = 0; o < 12; ++o) rg[o] = fmaf(v, reg_w[o * 256 + c], rg[o]);
  }
  const int hh = p / 160;
  const int ww = p - hh * 160;
  const float sx = ww * 4.0f, sy = hh * 4.0f;
  float odv[3] = {od0, od1, od2};
#pragma unroll
  for (int a = 0; a < 3; ++a) {
    float ar = (a == 0) ? 0.5f : ((a == 1) ? 1.0f : 2.0f);
    float sq = sqrtf(ar);
    float haf = 64.0f * sq, waf = 64.0f / sq;
    float ax1 = fminf(fmaxf(sx - waf * 0.5f, 0.f), 640.f);
    float ay1 = fminf(fmaxf(sy - haf * 0.5f, 0.f), 640.f);
    float ax2 = fminf(fmaxf(sx + waf * 0.5f, 0.f), 640.f);
    float ay2 = fminf(fmaxf(sy + haf * 0.5f, 0.f), 640.f);
    int ai = a * NPIX + p;
    out[OUT_ANCH + ai * 4 + 0] = ax1;
    out[OUT_ANCH + ai * 4 + 1] = ay1;
    out[OUT_ANCH + ai * 4 + 2] = ax2;
    out[OUT_ANCH + ai * 4 + 3] = ay2;
    float logit = odv[a] + det_b[a];
    out[OUT_OBJ + ai] = logit;
    float dx = rg[0 + a] + reg_b[0 + a];
    float dy = rg[3 + a] + reg_b[3 + a];
    float dw = rg[6 + a] + reg_b[6 + a];
    float dh = rg[9 + a] + reg_b[9 + a];
    out[OUT_DELT + ai * 4 + 0] = dx;
    out[OUT_DELT + ai * 4 + 1] = dy;
    out[OUT_DELT + ai * 4 + 2] = dw;
    out[OUT_DELT + ai * 4 + 3] = dh;
    float aw = ax2 - ax1, ah = ay2 - ay1;
    float cx = ax1 + 0.5f * aw, cy = ay1 + 0.5f * ah;
    float pcx = dx * aw + cx, pcy = dy * ah + cy;
    float pw = aw * expf(dw), ph = ah * expf(dh);
    props[ai * 4 + 0] = (double)fminf(fmaxf(pcx - 0.5f * pw, 0.f), 640.f);
    props[ai * 4 + 1] = (double)fminf(fmaxf(pcy - 0.5f * ph, 0.f), 640.f);
    props[ai * 4 + 2] = (double)fminf(fmaxf(pcx + 0.5f * pw, 0.f), 640.f);
    props[ai * 4 + 3] = (double)fminf(fmaxf(pcy + 0.5f * ph, 0.f), 640.f);
    keyf[ai] = (logit > 0.f) ? logit : -1e9f;   // sigmoid>0.5 <=> logit>0
  }
}

// ---------------------------------------------------------------- radix select (R11-proven)
__global__ __launch_bounds__(256) void hist_pass(const float* __restrict__ keyf,
                                                 unsigned* __restrict__ hist,
                                                 const SelState* __restrict__ st, int pass) {
  __shared__ unsigned lh[256];
  lh[threadIdx.x] = 0u;
  __syncthreads();
  unsigned prefix = st->prefix;
  int shift = 24 - 8 * pass;
  int i = blockIdx.x * 256 + threadIdx.x;   // 300*256 = 76800 exactly
  unsigned k = orderKey32(keyf[i]);
  bool ok = (pass == 0) || ((k >> (shift + 8)) == prefix);
  if (ok) atomicAdd(&lh[(k >> shift) & 255u], 1u);
  __syncthreads();
  unsigned c = lh[threadIdx.x];
  if (c) atomicAdd(&hist[threadIdx.x], c);
}

__global__ void pick_kernel(unsigned* __restrict__ hist, SelState* __restrict__ st) {
  if (threadIdx.x == 0 && blockIdx.x == 0) {
    int rem = st->remaining;
    unsigned cum = 0;
    int b = 0;
    for (int i = 255; i >= 0; --i) {
      unsigned h = hist[i];
      if (cum + h >= (unsigned)rem) { b = i; break; }
      cum += h;
    }
    st->prefix = (st->prefix << 8) | (unsigned)b;
    st->remaining = rem - (int)cum;
    for (int i = 0; i < 256; ++i) hist[i] = 0u;
  }
}

__global__ __launch_bounds__(256) void compact_kernel(const float* __restrict__ keyf,
                                                      SelState* __restrict__ st,
                                                      unsigned* __restrict__ candk,
                                                      unsigned* __restrict__ candi) {
  int i = blockIdx.x * 256 + threadIdx.x;
  if (i >= NANCH) return;
  unsigned k = orderKey32(keyf[i]);
  unsigned T = st->prefix;
  if (k > T) {
    int pos = atomicAdd(&st->cntHi, 1);
    if (pos < 2048) { candk[pos] = k; candi[pos] = (unsigned)i; }
  } else if (k == T) {
    int pos = atomicAdd(&st->cntEq, 1);
    if (pos < 2048) { candk[2048 + pos] = k; candi[2048 + pos] = (unsigned)i; }
  }
}

__global__ __launch_bounds__(1024) void sort_gather(const unsigned* __restrict__ candk,
                                                    const unsigned* __restrict__ candi,
                                                    const SelState* __restrict__ st,
                                                    const double* __restrict__ props,
                                                    float* __restrict__ tsc,
                                                    double* __restrict__ tbox) {
  __shared__ unsigned ka[4096];
  __shared__ unsigned ia[4096];
  int nHi = st->cntHi; if (nHi > 2048) nHi = 2048;
  int nEq = st->cntEq; if (nEq > 2048) nEq = 2048;
  for (int i = threadIdx.x; i < 4096; i += 1024) {
    bool real = (i < nHi) || (i >= 2048 && i < 2048 + nEq);
    ka[i] = real ? candk[i] : 0u;
    ia[i] = real ? candi[i] : 0xffffffffu;
  }
  __syncthreads();
  for (int k = 2; k <= 4096; k <<= 1) {
    for (int j = k >> 1; j > 0; j >>= 1) {
      for (int e = threadIdx.x; e < 4096; e += 1024) {
        int l = e ^ j;
        if (l > e) {
          unsigned ke = ka[e], kl = ka[l];
          unsigned ie = ia[e], il = ia[l];
          bool descending = ((e & k) == 0);
          bool lBetter = (kl > ke) || (kl == ke && il < ie);
          bool eBetter = (ke > kl) || (ke == kl && ie < il);
          bool sw = descending ? lBetter : eBetter;
          if (sw) { ka[e] = kl; ka[l] = ke; ia[e] = il; ia[l] = ie; }
        }
      }
      __syncthreads();
    }
  }
  for (int t = threadIdx.x; t < 2000; t += 1024) {
    unsigned idx = ia[t];
    if (idx < (unsigned)NANCH) {
      tsc[t] = key32ToFloat(ka[t]);
      tbox[t * 4 + 0] = props[(size_t)idx * 4 + 0];
      tbox[t * 4 + 1] = props[(size_t)idx * 4 + 1];
      tbox[t * 4 + 2] = props[(size_t)idx * 4 + 2];
      tbox[t * 4 + 3] = props[(size_t)idx * 4 + 3];
    } else {
      tsc[t] = -1e9f;     // invalid: never kept, never output
      tbox[t * 4 + 0] = 0.0; tbox[t * 4 + 1] = 0.0;
      tbox[t * 4 + 2] = 0.0; tbox[t * 4 + 3] = 0.0;
    }
  }
}

// ---------------------------------------------------------------- IoU bitmask (parallel; f64 formula verbatim from R11 NMS)
// word layout: mask32[i*64 + l] covers j in [l*32, l*32+32); bits only for j>i.
__global__ __launch_bounds__(256) void iou_mask(const double* __restrict__ tbox,
                                                unsigned* __restrict__ mask32) {
  int gid = blockIdx.x * 256 + threadIdx.x;
  if (gid >= 2000 * 64) return;
  int i = gid >> 6, l = gid & 63;
  int j0 = l * 32;
  unsigned m = 0u;
  if (j0 + 31 > i) {                       // word contains some j>i
    double bix = tbox[i * 4 + 0], biy = tbox[i * 4 + 1];
    double biz = tbox[i * 4 + 2], biw = tbox[i * 4 + 3];
    double areai = (biz - bix) * (biw - biy);
#pragma unroll 4
    for (int b = 0; b < 32; ++b) {
      int j = j0 + b;
      if (j >= 2000 || j <= i) continue;
      double bjx = tbox[j * 4 + 0], bjy = tbox[j * 4 + 1];
      double bjz = tbox[j * 4 + 2], bjw = tbox[j * 4 + 3];
      double xx1 = fmax(bix, bjx), yy1 = fmax(biy, bjy);
      double xx2 = fmin(biz, bjz), yy2 = fmin(biw, bjw);
      double iw = fmax(xx2 - xx1, 0.0), ih = fmax(yy2 - yy1, 0.0);
      double inter = iw * ih;
      double areaj = (bjz - bjx) * (bjw - bjy);
      double iou = inter / (areai + areaj - inter + 1e-9);
      if (iou > 0.7) m |= (1u << b);
    }
  }
  mask32[(size_t)i * 64 + l] = m;
}

// ---------------------------------------------------------------- greedy scan: single wave, zero barriers
// Equivalent to the validated fori_loop: keep[j] cleared iff some kept i<j has
// iou>0.7 (bits precomputed). Lockstep wave; LDS ops in program order.
__global__ __launch_bounds__(64) void nms_scan(const unsigned* __restrict__ mask32,
                                               const float* __restrict__ tsc,
                                               const double* __restrict__ tbox,
                                               float* __restrict__ out) {
  __shared__ unsigned kw[64];        // keep bitmask, u32 word per lane
  __shared__ unsigned wpfx[65];
  const int lane = threadIdx.x;
  kw[lane] = 0u;
  for (int i = lane; i < 2000; i += 64)
    if (tsc[i] > -5e8f) atomicOr(&kw[i >> 5], 1u << (i & 31));   // valid bits

  constexpr int PF = 8;
  unsigned mrow[PF];
#pragma unroll
  for (int q = 0; q < PF; ++q) mrow[q] = mask32[(size_t)q * 64 + lane];

  unsigned curw = kw[0];
  int curwi = 0;
  for (int i0 = 0; i0 < 2000; i0 += PF) {      // 2000 % 8 == 0
#pragma unroll
    for (int q = 0; q < PF; ++q) {
      int i = i0 + q;
      int wi = i >> 5;
      if (wi != curwi) { curw = kw[wi]; curwi = wi; }
      unsigned m = mrow[q];
      int ni = i + PF;
      if (ni < 2000) mrow[q] = mask32[(size_t)ni * 64 + lane];   // prefetch
      if ((curw >> (i & 31)) & 1u) {           // kept (uniform branch)
        kw[lane] &= ~m;                        // clear suppressed j's
        curw = kw[curwi];                      // re-sync cached word
      }
    }
  }

  if (lane == 0) {
    wpfx[0] = 0;
    for (int w = 0; w < 64; ++w) wpfx[w + 1] = wpfx[w] + __popc(kw[w]);
  }
  // single wave: lane0's writes ordered before subsequent reads
  for (int i = lane; i < 2000; i += 64) {
    if ((kw[i >> 5] >> (i & 31)) & 1u) {
      int r = (int)wpfx[i >> 5] + __popc(kw[i >> 5] & ((1u << (i & 31)) - 1u));
      if (r < 1000) {
        out[OUT_FL + r] = tsc[i];
        out[OUT_FB + r * 4 + 0] = (float)tbox[i * 4 + 0];
        out[OUT_FB + r * 4 + 1] = (float)tbox[i * 4 + 1];
        out[OUT_FB + r * 4 + 2] = (float)tbox[i * 4 + 2];
        out[OUT_FB + r * 4 + 3] = (float)tbox[i * 4 + 3];
      }
    }
  }
}

// ---------------------------------------------------------------- launch
extern "C" void kernel_launch(void* const* d_in, const int* in_sizes, int n_in,
                              void* d_out, int out_size, void* d_ws, size_t ws_size,
                              hipStream_t stream) {
  (void)in_sizes; (void)n_in; (void)out_size; (void)ws_size;
  const float* x      = (const float*)d_in[0];
  const float* conv_w = (const float*)d_in[1];
  const float* conv_b = (const float*)d_in[2];
  const float* gamma  = (const float*)d_in[3];
  const float* beta   = (const float*)d_in[4];
  const float* mean   = (const float*)d_in[5];
  const float* var    = (const float*)d_in[6];
  const float* det_w  = (const float*)d_in[7];
  const float* det_b  = (const float*)d_in[8];
  const float* reg_w  = (const float*)d_in[9];
  const float* reg_b  = (const float*)d_in[10];
  float* out = (float*)d_out;
  char* ws = (char*)d_ws;

  float*  y      = (float*)(ws + Y_OFF);
  double* props  = (double*)(ws + PROPS_OFF);
  float*  keyf   = (float*)(ws + KEYF_OFF);
  unsigned* candk = (unsigned*)(ws + CANDK_OFF);
  unsigned* candi = (unsigned*)(ws + CANDI_OFF);
  float*  tsc    = (float*)(ws + TSC_OFF);
  double* tbox   = (double*)(ws + TBOX_OFF);
  unsigned* hist = (unsigned*)(ws + HIST_OFF);
  SelState* st   = (SelState*)(ws + STATE_OFF);
  unsigned* mask32 = (unsigned*)(ws + MASK32_OFF);

  init_misc<<<16, 256, 0, stream>>>(out, hist, st);
  conv_tiled_f32r<<<dim3(100, 16), 256, 0, stream>>>(x, conv_w, conv_b, gamma, beta, mean, var, y);
  heads_kernel<<<100, 256, 0, stream>>>(y, det_w, det_b, reg_w, reg_b, out, props, keyf);
  for (int p = 0; p < 4; ++p) {
    hist_pass<<<300, 256, 0, stream>>>(keyf, hist, st, p);
    pick_kernel<<<1, 64, 0, stream>>>(hist, st);
  }
  compact_kernel<<<300, 256, 0, stream>>>(keyf, st, candk, candi);
  sort_gather<<<1, 1024, 0, stream>>>(candk, candi, st, props, tsc, tbox);
  iou_mask<<<500, 256, 0, stream>>>(tbox, mask32);
  nms_scan<<<1, 64, 0, stream>>>(mask32, tsc, tbox, out);
}